// Round 2
// baseline (312.913 us; speedup 1.0000x reference)
//
#include <hip/hip_runtime.h>

#define N_NODES 50000
#define N_EDGES 300000
#define N_TOT   350000   // edges + self-loops
#define D       256
#define MPAD    50048    // N_NODES padded to multiple of 64 for GEMM

typedef __attribute__((ext_vector_type(8))) short bf16x8;
typedef __attribute__((ext_vector_type(4))) float f32x4;

__device__ __forceinline__ float bf2f(unsigned short b) {
    union { unsigned u; float f; } v; v.u = ((unsigned)b) << 16; return v.f;
}
__device__ __forceinline__ unsigned short f2bf(float f) {
    union { float f; unsigned u; } v; v.f = f;
    unsigned u = v.u;
    unsigned r = (u + 0x7FFFu + ((u >> 16) & 1u)) >> 16;   // round-nearest-even
    return (unsigned short)r;
}

// ---- degree histogram over dst (self-loops included) ----
__global__ void hist_kernel(const int* __restrict__ ei, int* __restrict__ cnt) {
    int e = blockIdx.x * 256 + threadIdx.x;
    if (e >= N_TOT) return;
    int dst = (e < N_EDGES) ? ei[N_EDGES + e] : (e - N_EDGES);
    atomicAdd(&cnt[dst], 1);
}

// ---- deg_inv_sqrt: deg >= 1 always (self-loop) ----
__global__ void dis_kernel(const int* __restrict__ cnt, float* __restrict__ dis) {
    int i = blockIdx.x * 256 + threadIdx.x;
    if (i >= N_NODES) return;
    dis[i] = rsqrtf((float)cnt[i]);
}

// ---- exclusive scan of cnt -> rowptr (single block, 1024 thr, 4 elems/thr) ----
__global__ void scan_kernel(const int* __restrict__ cnt, int* __restrict__ rowptr) {
    __shared__ int wsum[16];
    __shared__ int chunk_total;
    int t = threadIdx.x;
    int lane = t & 63, wid = t >> 6;
    int carry = 0;
    if (t == 0) rowptr[0] = 0;
    for (int base = 0; base < N_NODES; base += 4096) {
        int i = base + t * 4;
        int4 v = {0, 0, 0, 0};
        if (i < N_NODES) v = *(const int4*)(cnt + i);   // N_NODES % 4 == 0
        int s0 = v.x, s1 = s0 + v.y, s2 = s1 + v.z, s3 = s2 + v.w;
        int s = s3;
        #pragma unroll
        for (int d = 1; d < 64; d <<= 1) {
            int u = __shfl_up(s, d, 64);
            if (lane >= d) s += u;
        }
        if (lane == 63) wsum[wid] = s;
        __syncthreads();
        if (t == 0) {
            int acc = 0;
            #pragma unroll
            for (int k = 0; k < 16; ++k) { int tmp = wsum[k]; wsum[k] = acc; acc += tmp; }
            chunk_total = acc;
        }
        __syncthreads();
        int excl = (s - s3) + wsum[wid] + carry;
        if (i < N_NODES) {
            rowptr[i + 1] = excl + s0;
            rowptr[i + 2] = excl + s1;
            rowptr[i + 3] = excl + s2;
            rowptr[i + 4] = excl + s3;
        }
        carry += chunk_total;
        __syncthreads();
    }
}

// ---- CSR fill: bucket edges by dst, precompute norm = dis[src]*dis[dst] ----
__global__ void fill_kernel(const int* __restrict__ ei, const int* __restrict__ rowptr,
                            int* __restrict__ fc, const float* __restrict__ dis,
                            int* __restrict__ esrc, float* __restrict__ enorm) {
    int e = blockIdx.x * 256 + threadIdx.x;
    if (e >= N_TOT) return;
    int src, dst;
    if (e < N_EDGES) { src = ei[e]; dst = ei[N_EDGES + e]; }
    else             { src = dst = e - N_EDGES; }
    int pos = rowptr[dst] + atomicAdd(&fc[dst], 1);
    esrc[pos]  = src;
    enorm[pos] = dis[src] * dis[dst];
}

// ---- transpose + cast W1,W2 (256x256 fp32) into bf16 Wt[n][k] ----
__global__ void transpose_kernel(const float* __restrict__ W1,
                                 const float* __restrict__ W2,
                                 unsigned short* __restrict__ Wt1,
                                 unsigned short* __restrict__ Wt2) {
    int b = blockIdx.x, t = threadIdx.x;
    if (b < D) Wt1[b * D + t] = f2bf(W1[t * D + b]);
    else       Wt2[(b - D) * D + t] = f2bf(W2[t * D + (b - D)]);
}

// ---- embed: h0 = relu(x @ We + be) in fp32, bf16 out; zero-fills pad rows ----
__global__ void embed_kernel(const float* __restrict__ x,
                             const float* __restrict__ We,
                             const float* __restrict__ be,
                             unsigned short* __restrict__ hA) {
    int t = threadIdx.x;
    float w[11];
    #pragma unroll
    for (int k = 0; k < 11; ++k) w[k] = We[k * D + t];
    float b = be[t];
    int node0 = blockIdx.x * 8;
    #pragma unroll
    for (int ni = 0; ni < 8; ++ni) {
        int node = node0 + ni;
        float acc = 0.f;
        if (node < N_NODES) {
            acc = b;
            #pragma unroll
            for (int k = 0; k < 11; ++k) acc += x[node * 11 + k] * w[k];
            acc = fmaxf(acc, 0.f);
        }
        hA[(size_t)node * D + t] = f2bf(acc);   // pad rows [N_NODES,MPAD) get 0
    }
}

// ---- GEMM: C[MPAD,256] = A[MPAD,256] @ W, W given as Wt[n][k]; bf16 in/out, fp32 acc ----
__global__ __launch_bounds__(256) void gemm_kernel(const unsigned short* __restrict__ A,
                                                   const unsigned short* __restrict__ Bt,
                                                   unsigned short* __restrict__ C) {
    int wid  = threadIdx.x >> 6;
    int lane = threadIdx.x & 63;
    int m0 = blockIdx.x * 64;
    int n0 = wid * 64;
    int q = lane >> 4, r = lane & 15;

    f32x4 acc[4][4] = {};
    const unsigned short* Ap = A  + (size_t)(m0 + r) * D + q * 8;
    const unsigned short* Bp = Bt + (size_t)(n0 + r) * D + q * 8;

    for (int kk = 0; kk < D; kk += 32) {
        bf16x8 a[4], b[4];
        #pragma unroll
        for (int mt = 0; mt < 4; ++mt)
            a[mt] = *(const bf16x8*)(Ap + (size_t)mt * 16 * D + kk);
        #pragma unroll
        for (int nt = 0; nt < 4; ++nt)
            b[nt] = *(const bf16x8*)(Bp + (size_t)nt * 16 * D + kk);
        #pragma unroll
        for (int mt = 0; mt < 4; ++mt)
            #pragma unroll
            for (int nt = 0; nt < 4; ++nt)
                acc[mt][nt] = __builtin_amdgcn_mfma_f32_16x16x32_bf16(a[mt], b[nt], acc[mt][nt], 0, 0, 0);
    }
    #pragma unroll
    for (int mt = 0; mt < 4; ++mt)
        #pragma unroll
        for (int nt = 0; nt < 4; ++nt) {
            int col  = n0 + nt * 16 + r;
            int rowb = m0 + mt * 16 + q * 4;
            #pragma unroll
            for (int i = 0; i < 4; ++i)
                C[(size_t)(rowb + i) * D + col] = f2bf(acc[mt][nt][i]);
        }
}

// ---- gather-aggregate: out[i] = (sum_{e: dst=i} hw[src]*norm) + bias (, relu) ----
// mode 1: relu, write bf16 to out_bf.  mode 0: no relu, write fp32 to out_f32.
__global__ __launch_bounds__(256) void agg_kernel(const unsigned short* __restrict__ hw,
                                                  const int* __restrict__ rowptr,
                                                  const int* __restrict__ esrc,
                                                  const float* __restrict__ enorm,
                                                  const float* __restrict__ bias,
                                                  unsigned short* __restrict__ out_bf,
                                                  float* __restrict__ out_f32,
                                                  int mode) {
    int wid  = threadIdx.x >> 6;
    int lane = threadIdx.x & 63;
    int node = blockIdx.x * 4 + wid;
    if (node >= N_NODES) return;
    int s0 = rowptr[node], s1 = rowptr[node + 1];
    int c = lane * 4;
    float a0 = 0.f, a1 = 0.f, a2 = 0.f, a3 = 0.f;
    for (int j = s0; j < s1; ++j) {
        int   src = esrc[j];
        float nm  = enorm[j];
        ushort4 hv = *(const ushort4*)(hw + (size_t)src * D + c);
        a0 += nm * bf2f(hv.x);
        a1 += nm * bf2f(hv.y);
        a2 += nm * bf2f(hv.z);
        a3 += nm * bf2f(hv.w);
    }
    float4 bv = *(const float4*)(bias + c);
    a0 += bv.x; a1 += bv.y; a2 += bv.z; a3 += bv.w;
    if (mode) {
        a0 = fmaxf(a0, 0.f); a1 = fmaxf(a1, 0.f);
        a2 = fmaxf(a2, 0.f); a3 = fmaxf(a3, 0.f);
        ushort4 ov = { f2bf(a0), f2bf(a1), f2bf(a2), f2bf(a3) };
        *(ushort4*)(out_bf + (size_t)node * D + c) = ov;
    } else {
        float4 ov = { a0, a1, a2, a3 };
        *(float4*)(out_f32 + (size_t)node * D + c) = ov;
    }
}

extern "C" void kernel_launch(void* const* d_in, const int* in_sizes, int n_in,
                              void* d_out, int out_size, void* d_ws, size_t ws_size,
                              hipStream_t stream) {
    const float* x  = (const float*)d_in[0];
    const int*   ei = (const int*)d_in[1];
    const float* We = (const float*)d_in[2];
    const float* be = (const float*)d_in[3];
    const float* W1 = (const float*)d_in[4];
    const float* b1 = (const float*)d_in[5];
    const float* W2 = (const float*)d_in[6];
    const float* b2 = (const float*)d_in[7];
    float* out = (float*)d_out;

    char* w = (char*)d_ws;
    auto alloc = [&](size_t bytes) {
        char* p = w;
        w += (bytes + 255) & ~(size_t)255;
        return p;
    };
    int*            cnt    = (int*)alloc((size_t)N_NODES * 4);
    int*            rowptr = (int*)alloc((size_t)(N_NODES + 1) * 4);
    float*          dis    = (float*)alloc((size_t)N_NODES * 4);
    int*            esrc   = (int*)alloc((size_t)N_TOT * 4);
    float*          enorm  = (float*)alloc((size_t)N_TOT * 4);
    unsigned short* Wt1    = (unsigned short*)alloc((size_t)D * D * 2);
    unsigned short* Wt2    = (unsigned short*)alloc((size_t)D * D * 2);
    unsigned short* hA     = (unsigned short*)alloc((size_t)MPAD * D * 2);
    unsigned short* hW     = (unsigned short*)alloc((size_t)MPAD * D * 2);
    // total ws use: ~55 MB

    hipMemsetAsync(cnt, 0, (size_t)N_NODES * 4, stream);
    hist_kernel<<<(N_TOT + 255) / 256, 256, 0, stream>>>(ei, cnt);
    dis_kernel<<<(N_NODES + 255) / 256, 256, 0, stream>>>(cnt, dis);
    scan_kernel<<<1, 1024, 0, stream>>>(cnt, rowptr);
    hipMemsetAsync(cnt, 0, (size_t)N_NODES * 4, stream);
    fill_kernel<<<(N_TOT + 255) / 256, 256, 0, stream>>>(ei, rowptr, cnt, dis, esrc, enorm);
    transpose_kernel<<<2 * D, 256, 0, stream>>>(W1, W2, Wt1, Wt2);

    embed_kernel<<<MPAD / 8, 256, 0, stream>>>(x, We, be, hA);

    gemm_kernel<<<MPAD / 64, 256, 0, stream>>>(hA, Wt1, hW);
    agg_kernel<<<(N_NODES + 3) / 4, 256, 0, stream>>>(hW, rowptr, esrc, enorm, b1, hA, nullptr, 1);

    gemm_kernel<<<MPAD / 64, 256, 0, stream>>>(hA, Wt2, hW);
    agg_kernel<<<(N_NODES + 3) / 4, 256, 0, stream>>>(hW, rowptr, esrc, enorm, b2, nullptr, out, 0);
}

// Round 3
// 283.007 us; speedup vs baseline: 1.1057x; 1.1057x over previous
//
#include <hip/hip_runtime.h>

#define N_NODES 50000
#define N_EDGES 300000
#define N_TOT   350000   // edges + self-loops
#define D       256
#define MPAD    50048    // N_NODES padded to multiple of 64 for GEMM

typedef __attribute__((ext_vector_type(8))) short bf16x8;
typedef __attribute__((ext_vector_type(4))) float f32x4;
typedef __attribute__((ext_vector_type(8))) unsigned short u16x8;

__device__ __forceinline__ float bf2f(unsigned short b) {
    union { unsigned u; float f; } v; v.u = ((unsigned)b) << 16; return v.f;
}
__device__ __forceinline__ unsigned short f2bf(float f) {
    union { float f; unsigned u; } v; v.f = f;
    unsigned u = v.u;
    unsigned r = (u + 0x7FFFu + ((u >> 16) & 1u)) >> 16;   // round-nearest-even
    return (unsigned short)r;
}

// ---- degree histogram over dst (self-loops included) ----
__global__ void hist_kernel(const int* __restrict__ ei, int* __restrict__ cnt) {
    int e = blockIdx.x * 256 + threadIdx.x;
    if (e >= N_TOT) return;
    int dst = (e < N_EDGES) ? ei[N_EDGES + e] : (e - N_EDGES);
    atomicAdd(&cnt[dst], 1);
}

// ---- deg_inv_sqrt: deg >= 1 always (self-loop) ----
__global__ void dis_kernel(const int* __restrict__ cnt, float* __restrict__ dis) {
    int i = blockIdx.x * 256 + threadIdx.x;
    if (i >= N_NODES) return;
    dis[i] = rsqrtf((float)cnt[i]);
}

// ---- exclusive scan of cnt -> rowptr (single block, 1024 thr, 4 elems/thr) ----
__global__ void scan_kernel(const int* __restrict__ cnt, int* __restrict__ rowptr) {
    __shared__ int wsum[16];
    __shared__ int chunk_total;
    int t = threadIdx.x;
    int lane = t & 63, wid = t >> 6;
    int carry = 0;
    if (t == 0) rowptr[0] = 0;
    for (int base = 0; base < N_NODES; base += 4096) {
        int i = base + t * 4;
        int4 v = {0, 0, 0, 0};
        if (i < N_NODES) v = *(const int4*)(cnt + i);   // N_NODES % 4 == 0
        int s0 = v.x, s1 = s0 + v.y, s2 = s1 + v.z, s3 = s2 + v.w;
        int s = s3;
        #pragma unroll
        for (int d = 1; d < 64; d <<= 1) {
            int u = __shfl_up(s, d, 64);
            if (lane >= d) s += u;
        }
        if (lane == 63) wsum[wid] = s;
        __syncthreads();
        if (t == 0) {
            int acc = 0;
            #pragma unroll
            for (int k = 0; k < 16; ++k) { int tmp = wsum[k]; wsum[k] = acc; acc += tmp; }
            chunk_total = acc;
        }
        __syncthreads();
        int excl = (s - s3) + wsum[wid] + carry;
        if (i < N_NODES) {
            rowptr[i + 1] = excl + s0;
            rowptr[i + 2] = excl + s1;
            rowptr[i + 3] = excl + s2;
            rowptr[i + 4] = excl + s3;
        }
        carry += chunk_total;
        __syncthreads();
    }
}

// ---- CSR fill: bucket edges by dst, precompute norm = dis[src]*dis[dst] ----
__global__ void fill_kernel(const int* __restrict__ ei, const int* __restrict__ rowptr,
                            int* __restrict__ fc, const float* __restrict__ dis,
                            int* __restrict__ esrc, float* __restrict__ enorm) {
    int e = blockIdx.x * 256 + threadIdx.x;
    if (e >= N_TOT) return;
    int src, dst;
    if (e < N_EDGES) { src = ei[e]; dst = ei[N_EDGES + e]; }
    else             { src = dst = e - N_EDGES; }
    int pos = rowptr[dst] + atomicAdd(&fc[dst], 1);
    esrc[pos]  = src;
    enorm[pos] = dis[src] * dis[dst];
}

// ---- transpose + cast W1,W2 (256x256 fp32) into bf16 Wt[n][k] ----
__global__ void transpose_kernel(const float* __restrict__ W1,
                                 const float* __restrict__ W2,
                                 unsigned short* __restrict__ Wt1,
                                 unsigned short* __restrict__ Wt2) {
    int b = blockIdx.x, t = threadIdx.x;
    if (b < D) Wt1[b * D + t] = f2bf(W1[t * D + b]);
    else       Wt2[(b - D) * D + t] = f2bf(W2[t * D + (b - D)]);
}

// ---- embed: h0 = relu(x @ We + be) in fp32, bf16 out; zero-fills pad rows ----
__global__ void embed_kernel(const float* __restrict__ x,
                             const float* __restrict__ We,
                             const float* __restrict__ be,
                             unsigned short* __restrict__ hA) {
    int t = threadIdx.x;
    float w[11];
    #pragma unroll
    for (int k = 0; k < 11; ++k) w[k] = We[k * D + t];
    float b = be[t];
    int node0 = blockIdx.x * 8;
    #pragma unroll
    for (int ni = 0; ni < 8; ++ni) {
        int node = node0 + ni;
        float acc = 0.f;
        if (node < N_NODES) {
            acc = b;
            #pragma unroll
            for (int k = 0; k < 11; ++k) acc += x[node * 11 + k] * w[k];
            acc = fmaxf(acc, 0.f);
        }
        hA[(size_t)node * D + t] = f2bf(acc);   // pad rows [N_NODES,MPAD) get 0
    }
}

// ---- GEMM: C[MPAD,256] = A[MPAD,256] @ W, W given as Wt[n][k]; bf16 in/out, fp32 acc ----
__global__ __launch_bounds__(256) void gemm_kernel(const unsigned short* __restrict__ A,
                                                   const unsigned short* __restrict__ Bt,
                                                   unsigned short* __restrict__ C) {
    int wid  = threadIdx.x >> 6;
    int lane = threadIdx.x & 63;
    int m0 = blockIdx.x * 64;
    int n0 = wid * 64;
    int q = lane >> 4, r = lane & 15;

    f32x4 acc[4][4] = {};
    const unsigned short* Ap = A  + (size_t)(m0 + r) * D + q * 8;
    const unsigned short* Bp = Bt + (size_t)(n0 + r) * D + q * 8;

    for (int kk = 0; kk < D; kk += 32) {
        bf16x8 a[4], b[4];
        #pragma unroll
        for (int mt = 0; mt < 4; ++mt)
            a[mt] = *(const bf16x8*)(Ap + (size_t)mt * 16 * D + kk);
        #pragma unroll
        for (int nt = 0; nt < 4; ++nt)
            b[nt] = *(const bf16x8*)(Bp + (size_t)nt * 16 * D + kk);
        #pragma unroll
        for (int mt = 0; mt < 4; ++mt)
            #pragma unroll
            for (int nt = 0; nt < 4; ++nt)
                acc[mt][nt] = __builtin_amdgcn_mfma_f32_16x16x32_bf16(a[mt], b[nt], acc[mt][nt], 0, 0, 0);
    }
    #pragma unroll
    for (int mt = 0; mt < 4; ++mt)
        #pragma unroll
        for (int nt = 0; nt < 4; ++nt) {
            int col  = n0 + nt * 16 + r;
            int rowb = m0 + mt * 16 + q * 4;
            #pragma unroll
            for (int i = 0; i < 4; ++i)
                C[(size_t)(rowb + i) * D + col] = f2bf(acc[mt][nt][i]);
        }
}

// ---- gather-aggregate v2: wave per node, 2 edges per loop trip, 16B/lane ----
// Edge indices/norms prefetched lane-parallel and broadcast via shfl (no index
// loads in the dependent chain). half 0 handles even edges, half 1 odd edges;
// each half-wave (32 lanes x 16B) reads one full 512B row per trip.
// mode 1: relu, write bf16 to out_bf.  mode 0: no relu, write fp32 to out_f32.
__global__ __launch_bounds__(256) void agg_kernel(const unsigned short* __restrict__ hw,
                                                  const int* __restrict__ rowptr,
                                                  const int* __restrict__ esrc,
                                                  const float* __restrict__ enorm,
                                                  const float* __restrict__ bias,
                                                  unsigned short* __restrict__ out_bf,
                                                  float* __restrict__ out_f32,
                                                  int mode) {
    int wid  = threadIdx.x >> 6;
    int lane = threadIdx.x & 63;
    int node = blockIdx.x * 4 + wid;
    if (node >= N_NODES) return;
    int s0 = rowptr[node], s1 = rowptr[node + 1];
    int half = lane >> 5, hl = lane & 31;

    float acc[8] = {};
    for (int base = s0; base < s1; base += 64) {   // one trip in practice (deg << 64)
        int ec = s1 - base; if (ec > 64) ec = 64;
        int   srcl = 0; float nml = 0.f;
        if (lane < ec) { srcl = esrc[base + lane]; nml = enorm[base + lane]; }
        int it = (ec + 1) >> 1;
        for (int i = 0; i < it; ++i) {
            int   e  = 2 * i + half;               // e <= ec; lanes >= ec hold nm=0
            int   s  = __shfl(srcl, e, 64);
            float nm = __shfl(nml, e, 64);
            u16x8 hv = *(const u16x8*)(hw + (size_t)s * D + hl * 8);
            #pragma unroll
            for (int k = 0; k < 8; ++k) acc[k] += nm * bf2f(hv[k]);
        }
    }
    #pragma unroll
    for (int k = 0; k < 8; ++k) acc[k] += __shfl_xor(acc[k], 32, 64);

    if (lane < 32) {
        int c = hl * 8;
        float4 bv0 = *(const float4*)(bias + c);
        float4 bv1 = *(const float4*)(bias + c + 4);
        acc[0] += bv0.x; acc[1] += bv0.y; acc[2] += bv0.z; acc[3] += bv0.w;
        acc[4] += bv1.x; acc[5] += bv1.y; acc[6] += bv1.z; acc[7] += bv1.w;
        if (mode) {
            u16x8 ov;
            #pragma unroll
            for (int k = 0; k < 8; ++k) ov[k] = f2bf(fmaxf(acc[k], 0.f));
            *(u16x8*)(out_bf + (size_t)node * D + c) = ov;
        } else {
            float4 o0 = { acc[0], acc[1], acc[2], acc[3] };
            float4 o1 = { acc[4], acc[5], acc[6], acc[7] };
            *(float4*)(out_f32 + (size_t)node * D + c)     = o0;
            *(float4*)(out_f32 + (size_t)node * D + c + 4) = o1;
        }
    }
}

extern "C" void kernel_launch(void* const* d_in, const int* in_sizes, int n_in,
                              void* d_out, int out_size, void* d_ws, size_t ws_size,
                              hipStream_t stream) {
    const float* x  = (const float*)d_in[0];
    const int*   ei = (const int*)d_in[1];
    const float* We = (const float*)d_in[2];
    const float* be = (const float*)d_in[3];
    const float* W1 = (const float*)d_in[4];
    const float* b1 = (const float*)d_in[5];
    const float* W2 = (const float*)d_in[6];
    const float* b2 = (const float*)d_in[7];
    float* out = (float*)d_out;

    char* w = (char*)d_ws;
    auto alloc = [&](size_t bytes) {
        char* p = w;
        w += (bytes + 255) & ~(size_t)255;
        return p;
    };
    int*            cnt    = (int*)alloc((size_t)N_NODES * 4);
    int*            rowptr = (int*)alloc((size_t)(N_NODES + 1) * 4);
    float*          dis    = (float*)alloc((size_t)N_NODES * 4);
    int*            esrc   = (int*)alloc((size_t)N_TOT * 4);
    float*          enorm  = (float*)alloc((size_t)N_TOT * 4);
    unsigned short* Wt1    = (unsigned short*)alloc((size_t)D * D * 2);
    unsigned short* Wt2    = (unsigned short*)alloc((size_t)D * D * 2);
    unsigned short* hA     = (unsigned short*)alloc((size_t)MPAD * D * 2);
    unsigned short* hW     = (unsigned short*)alloc((size_t)MPAD * D * 2);
    // total ws use: ~55 MB

    hipMemsetAsync(cnt, 0, (size_t)N_NODES * 4, stream);
    hist_kernel<<<(N_TOT + 255) / 256, 256, 0, stream>>>(ei, cnt);
    dis_kernel<<<(N_NODES + 255) / 256, 256, 0, stream>>>(cnt, dis);
    scan_kernel<<<1, 1024, 0, stream>>>(cnt, rowptr);
    hipMemsetAsync(cnt, 0, (size_t)N_NODES * 4, stream);
    fill_kernel<<<(N_TOT + 255) / 256, 256, 0, stream>>>(ei, rowptr, cnt, dis, esrc, enorm);
    transpose_kernel<<<2 * D, 256, 0, stream>>>(W1, W2, Wt1, Wt2);

    embed_kernel<<<MPAD / 8, 256, 0, stream>>>(x, We, be, hA);

    gemm_kernel<<<MPAD / 64, 256, 0, stream>>>(hA, Wt1, hW);
    agg_kernel<<<(N_NODES + 3) / 4, 256, 0, stream>>>(hW, rowptr, esrc, enorm, b1, hA, nullptr, 1);

    gemm_kernel<<<MPAD / 64, 256, 0, stream>>>(hA, Wt2, hW);
    agg_kernel<<<(N_NODES + 3) / 4, 256, 0, stream>>>(hW, rowptr, esrc, enorm, b2, nullptr, out, 0);
}

// Round 4
// 242.036 us; speedup vs baseline: 1.2928x; 1.1693x over previous
//
#include <hip/hip_runtime.h>

#define N_NODES 50000
#define N_EDGES 300000
#define N_TOT   350000   // edges + self-loops
#define D       256
#define MPAD    50048    // N_NODES padded to multiple of 128 for GEMM (128*391)
#define SCAN_B  196      // ceil(50000/256)

typedef __attribute__((ext_vector_type(8))) short bf16x8;
typedef __attribute__((ext_vector_type(4))) float f32x4;
typedef __attribute__((ext_vector_type(8))) unsigned short u16x8;

__device__ __forceinline__ float bf2f(unsigned short b) {
    union { unsigned u; float f; } v; v.u = ((unsigned)b) << 16; return v.f;
}
__device__ __forceinline__ unsigned short f2bf(float f) {
    union { float f; unsigned u; } v; v.f = f;
    unsigned u = v.u;
    unsigned r = (u + 0x7FFFu + ((u >> 16) & 1u)) >> 16;   // round-nearest-even
    return (unsigned short)r;
}
__device__ __forceinline__ void g2lds16(const unsigned short* g, unsigned short* l) {
    __builtin_amdgcn_global_load_lds(
        (const __attribute__((address_space(1))) void*)g,
        (__attribute__((address_space(3))) void*)l, 16, 0, 0);
}

// ---- degree histogram over dst (self-loops included) ----
__global__ void hist_kernel(const int* __restrict__ ei, int* __restrict__ cnt) {
    int e = blockIdx.x * 256 + threadIdx.x;
    if (e >= N_TOT) return;
    int dst = (e < N_EDGES) ? ei[N_EDGES + e] : (e - N_EDGES);
    atomicAdd(&cnt[dst], 1);
}

// ---- deg_inv_sqrt: deg >= 1 always (self-loop) ----
__global__ void dis_kernel(const int* __restrict__ cnt, float* __restrict__ dis) {
    int i = blockIdx.x * 256 + threadIdx.x;
    if (i >= N_NODES) return;
    dis[i] = rsqrtf((float)cnt[i]);
}

// ---- decoupled 3-phase exclusive scan of cnt -> rowptr ----
__global__ void scan1_kernel(const int* __restrict__ cnt, int* __restrict__ locs,
                             int* __restrict__ bsum) {
    __shared__ int ws[4];
    int t = threadIdx.x, lane = t & 63, wv = t >> 6;
    int i = blockIdx.x * 256 + t;
    int v = (i < N_NODES) ? cnt[i] : 0;
    int s = v;
    #pragma unroll
    for (int d = 1; d < 64; d <<= 1) {
        int u = __shfl_up(s, d, 64);
        if (lane >= d) s += u;
    }
    if (lane == 63) ws[wv] = s;
    __syncthreads();
    int off = 0;
    #pragma unroll
    for (int k = 0; k < 4; ++k) if (k < wv) off += ws[k];
    s += off;
    if (i < N_NODES) locs[i] = s;                 // inclusive local scan
    if (t == 255) bsum[blockIdx.x] = s;           // block total
}
__global__ void scan2_kernel(int* __restrict__ bsum) {   // 1 block, 256 thr
    __shared__ int ws[4];
    int t = threadIdx.x, lane = t & 63, wv = t >> 6;
    int v = (t < SCAN_B) ? bsum[t] : 0;
    int s = v;
    #pragma unroll
    for (int d = 1; d < 64; d <<= 1) {
        int u = __shfl_up(s, d, 64);
        if (lane >= d) s += u;
    }
    if (lane == 63) ws[wv] = s;
    __syncthreads();
    int off = 0;
    #pragma unroll
    for (int k = 0; k < 4; ++k) if (k < wv) off += ws[k];
    s += off;
    if (t < SCAN_B) bsum[t] = s - v;              // exclusive block offsets
}
__global__ void scan3_kernel(const int* __restrict__ locs, const int* __restrict__ bsum,
                             int* __restrict__ rowptr) {
    int i = blockIdx.x * 256 + threadIdx.x;
    if (i == 0) rowptr[0] = 0;
    if (i < N_NODES) rowptr[i + 1] = locs[i] + bsum[i >> 8];
}

// ---- CSR fill: bucket edges by dst, precompute norm = dis[src]*dis[dst] ----
__global__ void fill_kernel(const int* __restrict__ ei, const int* __restrict__ rowptr,
                            int* __restrict__ fc, const float* __restrict__ dis,
                            int* __restrict__ esrc, float* __restrict__ enorm) {
    int e = blockIdx.x * 256 + threadIdx.x;
    if (e >= N_TOT) return;
    int src, dst;
    if (e < N_EDGES) { src = ei[e]; dst = ei[N_EDGES + e]; }
    else             { src = dst = e - N_EDGES; }
    int pos = rowptr[dst] + atomicAdd(&fc[dst], 1);
    esrc[pos]  = src;
    enorm[pos] = dis[src] * dis[dst];
}

// ---- transpose + cast W1,W2 (256x256 fp32) into bf16 Wt[n][k] ----
__global__ void transpose_kernel(const float* __restrict__ W1,
                                 const float* __restrict__ W2,
                                 unsigned short* __restrict__ Wt1,
                                 unsigned short* __restrict__ Wt2) {
    int b = blockIdx.x, t = threadIdx.x;
    if (b < D) Wt1[b * D + t] = f2bf(W1[t * D + b]);
    else       Wt2[(b - D) * D + t] = f2bf(W2[t * D + (b - D)]);
}

// ---- embed: h0 = relu(x @ We + be) in fp32, bf16 out; zero-fills pad rows ----
__global__ void embed_kernel(const float* __restrict__ x,
                             const float* __restrict__ We,
                             const float* __restrict__ be,
                             unsigned short* __restrict__ hA) {
    int t = threadIdx.x;
    float w[11];
    #pragma unroll
    for (int k = 0; k < 11; ++k) w[k] = We[k * D + t];
    float b = be[t];
    int node0 = blockIdx.x * 8;
    #pragma unroll
    for (int ni = 0; ni < 8; ++ni) {
        int node = node0 + ni;
        float acc = 0.f;
        if (node < N_NODES) {
            acc = b;
            #pragma unroll
            for (int k = 0; k < 11; ++k) acc += x[node * 11 + k] * w[k];
            acc = fmaxf(acc, 0.f);
        }
        hA[(size_t)node * D + t] = f2bf(acc);   // pad rows [N_NODES,MPAD) get 0
    }
}

// ---- GEMM (m97-style): C[MPAD,256] = A @ W, W as Wt[n][k]; 128x128 tile, BK=32,
//      global_load_lds width-16 staging, ds_read_b128 frags, bf16 in/out, fp32 acc ----
__global__ __launch_bounds__(256) void gemm_kernel(const unsigned short* __restrict__ A,
                                                   const unsigned short* __restrict__ Bt,
                                                   unsigned short* __restrict__ C) {
    __shared__ unsigned short lA[128 * 32];
    __shared__ unsigned short lB[128 * 32];
    int t = threadIdx.x;
    int wv = t >> 6, lane = t & 63;
    int m0 = blockIdx.x * 128;
    int n0 = blockIdx.y * 128;
    int moff = (wv & 1) * 64, noff = (wv >> 1) * 64;
    int q = lane >> 4, r = lane & 15;

    int srow = t >> 2;            // 0..63: staged row within half-tile
    int skof = (t & 3) * 8;       // k-offset in elements (4 threads x 8 = 32)

    const unsigned short* Ag0 = A  + (size_t)(m0 + srow) * D + skof;
    const unsigned short* Ag1 = Ag0 + (size_t)64 * D;
    const unsigned short* Bg0 = Bt + (size_t)(n0 + srow) * D + skof;
    const unsigned short* Bg1 = Bg0 + (size_t)64 * D;
    unsigned short* lA0 = lA + t * 8;          // lane-contiguous: row-major [128][32]
    unsigned short* lA1 = lA0 + 64 * 32;
    unsigned short* lB0 = lB + t * 8;
    unsigned short* lB1 = lB0 + 64 * 32;

    f32x4 acc[4][4] = {};
    for (int kk = 0; kk < D; kk += 32) {
        __syncthreads();                       // previous compute done before overwrite
        g2lds16(Ag0 + kk, lA0);
        g2lds16(Ag1 + kk, lA1);
        g2lds16(Bg0 + kk, lB0);
        g2lds16(Bg1 + kk, lB1);
        __syncthreads();                       // compiler drains vmcnt before barrier
        bf16x8 a[4], b[4];
        #pragma unroll
        for (int mt = 0; mt < 4; ++mt)
            a[mt] = *(const bf16x8*)(lA + (moff + mt * 16 + r) * 32 + q * 8);
        #pragma unroll
        for (int nt = 0; nt < 4; ++nt)
            b[nt] = *(const bf16x8*)(lB + (noff + nt * 16 + r) * 32 + q * 8);
        #pragma unroll
        for (int mt = 0; mt < 4; ++mt)
            #pragma unroll
            for (int nt = 0; nt < 4; ++nt)
                acc[mt][nt] = __builtin_amdgcn_mfma_f32_16x16x32_bf16(a[mt], b[nt], acc[mt][nt], 0, 0, 0);
    }
    #pragma unroll
    for (int mt = 0; mt < 4; ++mt)
        #pragma unroll
        for (int nt = 0; nt < 4; ++nt) {
            int col  = n0 + noff + nt * 16 + r;
            int rowb = m0 + moff + mt * 16 + q * 4;
            #pragma unroll
            for (int i = 0; i < 4; ++i)
                C[(size_t)(rowb + i) * D + col] = f2bf(acc[mt][nt][i]);
        }
}

// ---- gather-aggregate: wave per node, 2 edges per trip, 16B/lane ----
__global__ __launch_bounds__(256) void agg_kernel(const unsigned short* __restrict__ hw,
                                                  const int* __restrict__ rowptr,
                                                  const int* __restrict__ esrc,
                                                  const float* __restrict__ enorm,
                                                  const float* __restrict__ bias,
                                                  unsigned short* __restrict__ out_bf,
                                                  float* __restrict__ out_f32,
                                                  int mode) {
    int wid  = threadIdx.x >> 6;
    int lane = threadIdx.x & 63;
    int node = blockIdx.x * 4 + wid;
    if (node >= N_NODES) return;
    int s0 = rowptr[node], s1 = rowptr[node + 1];
    int half = lane >> 5, hl = lane & 31;

    float acc[8] = {};
    for (int base = s0; base < s1; base += 64) {   // one trip in practice (deg << 64)
        int ec = s1 - base; if (ec > 64) ec = 64;
        int   srcl = 0; float nml = 0.f;
        if (lane < ec) { srcl = esrc[base + lane]; nml = enorm[base + lane]; }
        int it = (ec + 1) >> 1;
        for (int i = 0; i < it; ++i) {
            int   e  = 2 * i + half;
            int   s  = __shfl(srcl, e, 64);
            float nm = __shfl(nml, e, 64);
            u16x8 hv = *(const u16x8*)(hw + (size_t)s * D + hl * 8);
            #pragma unroll
            for (int k = 0; k < 8; ++k) acc[k] += nm * bf2f(hv[k]);
        }
    }
    #pragma unroll
    for (int k = 0; k < 8; ++k) acc[k] += __shfl_xor(acc[k], 32, 64);

    if (lane < 32) {
        int c = hl * 8;
        float4 bv0 = *(const float4*)(bias + c);
        float4 bv1 = *(const float4*)(bias + c + 4);
        acc[0] += bv0.x; acc[1] += bv0.y; acc[2] += bv0.z; acc[3] += bv0.w;
        acc[4] += bv1.x; acc[5] += bv1.y; acc[6] += bv1.z; acc[7] += bv1.w;
        if (mode) {
            u16x8 ov;
            #pragma unroll
            for (int k = 0; k < 8; ++k) ov[k] = f2bf(fmaxf(acc[k], 0.f));
            *(u16x8*)(out_bf + (size_t)node * D + c) = ov;
        } else {
            float4 o0 = { acc[0], acc[1], acc[2], acc[3] };
            float4 o1 = { acc[4], acc[5], acc[6], acc[7] };
            *(float4*)(out_f32 + (size_t)node * D + c)     = o0;
            *(float4*)(out_f32 + (size_t)node * D + c + 4) = o1;
        }
    }
}

extern "C" void kernel_launch(void* const* d_in, const int* in_sizes, int n_in,
                              void* d_out, int out_size, void* d_ws, size_t ws_size,
                              hipStream_t stream) {
    const float* x  = (const float*)d_in[0];
    const int*   ei = (const int*)d_in[1];
    const float* We = (const float*)d_in[2];
    const float* be = (const float*)d_in[3];
    const float* W1 = (const float*)d_in[4];
    const float* b1 = (const float*)d_in[5];
    const float* W2 = (const float*)d_in[6];
    const float* b2 = (const float*)d_in[7];
    float* out = (float*)d_out;

    char* w = (char*)d_ws;
    auto alloc = [&](size_t bytes) {
        char* p = w;
        w += (bytes + 255) & ~(size_t)255;
        return p;
    };
    int*            cnt    = (int*)alloc((size_t)N_NODES * 4);
    int*            rowptr = (int*)alloc((size_t)(N_NODES + 1) * 4);
    int*            locs   = (int*)alloc((size_t)N_NODES * 4);
    int*            bsum   = (int*)alloc((size_t)SCAN_B * 4);
    float*          dis    = (float*)alloc((size_t)N_NODES * 4);
    int*            esrc   = (int*)alloc((size_t)N_TOT * 4);
    float*          enorm  = (float*)alloc((size_t)N_TOT * 4);
    unsigned short* Wt1    = (unsigned short*)alloc((size_t)D * D * 2);
    unsigned short* Wt2    = (unsigned short*)alloc((size_t)D * D * 2);
    unsigned short* hA     = (unsigned short*)alloc((size_t)MPAD * D * 2);
    unsigned short* hW     = (unsigned short*)alloc((size_t)MPAD * D * 2);
    // total ws use: ~55 MB

    hipMemsetAsync(cnt, 0, (size_t)N_NODES * 4, stream);
    hist_kernel<<<(N_TOT + 255) / 256, 256, 0, stream>>>(ei, cnt);
    dis_kernel<<<(N_NODES + 255) / 256, 256, 0, stream>>>(cnt, dis);
    scan1_kernel<<<SCAN_B, 256, 0, stream>>>(cnt, locs, bsum);
    scan2_kernel<<<1, 256, 0, stream>>>(bsum);
    scan3_kernel<<<SCAN_B, 256, 0, stream>>>(locs, bsum, rowptr);
    hipMemsetAsync(cnt, 0, (size_t)N_NODES * 4, stream);
    fill_kernel<<<(N_TOT + 255) / 256, 256, 0, stream>>>(ei, rowptr, cnt, dis, esrc, enorm);
    transpose_kernel<<<2 * D, 256, 0, stream>>>(W1, W2, Wt1, Wt2);

    embed_kernel<<<MPAD / 8, 256, 0, stream>>>(x, We, be, hA);

    dim3 ggrid(MPAD / 128, 2);
    gemm_kernel<<<ggrid, 256, 0, stream>>>(hA, Wt1, hW);
    agg_kernel<<<(N_NODES + 3) / 4, 256, 0, stream>>>(hW, rowptr, esrc, enorm, b1, hA, nullptr, 1);

    gemm_kernel<<<ggrid, 256, 0, stream>>>(hA, Wt2, hW);
    agg_kernel<<<(N_NODES + 3) / 4, 256, 0, stream>>>(hW, rowptr, esrc, enorm, b2, nullptr, out, 0);
}